// Round 9
// baseline (212.946 us; speedup 1.0000x reference)
//
#include <hip/hip_runtime.h>
#include <hip/hip_bf16.h>

#define D_MODEL 1024
#define NHEAD   16
#define HDIM    64
#define SEQQ    2048
#define NBATCH  2
#define MROWS   (NBATCH * SEQQ)   // 4096

typedef unsigned short u16;
typedef __attribute__((ext_vector_type(8))) short short8;   // 8 bf16 (4 VGPRs)
typedef __attribute__((ext_vector_type(4))) float floatx4;  // 4 fp32 acc

__device__ __forceinline__ u16 f2b(float f) {
    union { __hip_bfloat16 h; u16 u; } cv;
    cv.h = __float2bfloat16(f);
    return cv.u;
}
__device__ __forceinline__ float b2f(u16 u) {
    return __uint_as_float(((unsigned int)u) << 16);
}
__device__ __forceinline__ short8 load8(const u16* p) {
    return *reinterpret_cast<const short8*>(p);
}
__device__ __forceinline__ void async_cp16(const void* g, void* l) {
    __builtin_amdgcn_global_load_lds(
        (const __attribute__((address_space(1))) void*)g,
        (__attribute__((address_space(3))) void*)l, 16, 0, 0);
}

// ---------------- cvt + rope-table build, one dispatch ----------------
// z 0..3: X quarters fp32->bf16; z 4..7: weights; z 8: sincos table from tpos.
__global__ void cvt_all(const float* __restrict__ X,
                        const float* __restrict__ w0, const float* __restrict__ w1,
                        const float* __restrict__ w2, const float* __restrict__ w3,
                        const int* __restrict__ tpos,
                        u16* __restrict__ xo,
                        u16* __restrict__ o0, u16* __restrict__ o1,
                        u16* __restrict__ o2, u16* __restrict__ o3,
                        float2* __restrict__ tbl) {
    const int z = blockIdx.y;
    if (z == 8) {                      // rope table: [s][j] -> (cos, sin)
        const int i = blockIdx.x * 256 + threadIdx.x;   // 2048*32 = 65536 entries
        if (i >= SEQQ * 32) return;
        const int s = i >> 5, j = i & 31;
        const float p = (float)tpos[s];
        const float inv = expf(-(float)j * (9.210340371976184f / 32.0f));
        float sn, cs;
        sincosf(p * inv, &sn, &cs);
        tbl[i] = make_float2(cs, sn);
        return;
    }
    const int n4 = (D_MODEL * D_MODEL) / 4;   // 262144 float4 per segment
    const float* in;
    u16* out;
    if (z < 4) { in = X + (size_t)z * n4 * 4;  out = xo + (size_t)z * n4 * 4; }
    else {
        in  = (z == 4) ? w0 : (z == 5) ? w1 : (z == 6) ? w2 : w3;
        out = (z == 4) ? o0 : (z == 5) ? o1 : (z == 6) ? o2 : o3;
    }
    const int i = blockIdx.x * 256 + threadIdx.x;
    float4 v = reinterpret_cast<const float4*>(in)[i];
    ushort4 o;
    o.x = f2b(v.x); o.y = f2b(v.y); o.z = f2b(v.z); o.w = f2b(v.w);
    reinterpret_cast<ushort4*>(out)[i] = o;
}

// ---------------- QKV GEMM with fused RoPE epilogue ----------------
// z=0: Q = X Wq^T, rope + 0.125 scale, write Qt [b,h,s,d]
// z=1: K = X Wk^T, rope,                write Kt [b,h,s,d]
// z=2: V = X Wv^T, plain bf16,          write Vraw [b,s,h*d]
__global__ __launch_bounds__(256) void gemm_qkv(
    const u16* __restrict__ A,
    const u16* __restrict__ B0, const u16* __restrict__ B1, const u16* __restrict__ B2,
    u16* __restrict__ Qt, u16* __restrict__ Kt, u16* __restrict__ Vraw,
    const float2* __restrict__ tbl)
{
    const int K = D_MODEL, N = D_MODEL;
    const u16* Bt = (blockIdx.z == 0) ? B0 : (blockIdx.z == 1 ? B1 : B2);

    __shared__ __attribute__((aligned(16))) u16 As[128 * 32];
    __shared__ __attribute__((aligned(16))) u16 Bs[128 * 32];

    const int tid  = threadIdx.x;
    const int w    = tid >> 6;
    const int lane = tid & 63;
    const int l15  = lane & 15;
    const int quad = lane >> 4;
    const int wm   = w >> 1, wn = w & 1;
    const int tm   = blockIdx.x * 128, tn = blockIdx.y * 128;

    floatx4 acc[4][4];
#pragma unroll
    for (int i = 0; i < 4; i++)
#pragma unroll
        for (int j = 0; j < 4; j++) {
            floatx4 z = {0.f, 0.f, 0.f, 0.f};
            acc[i][j] = z;
        }

    const int srow = lane >> 2;
    const int scol = (lane & 3) * 8;

    for (int k0 = 0; k0 < K; k0 += 32) {
#pragma unroll
        for (int ch = w; ch < 8; ch += 4) {
            async_cp16(A  + (size_t)(tm + ch * 16 + srow) * K + k0 + scol, &As[ch * 512]);
            async_cp16(Bt + (size_t)(tn + ch * 16 + srow) * K + k0 + scol, &Bs[ch * 512]);
        }
        __syncthreads();

        short8 af[4], bfr[4];
#pragma unroll
        for (int mi = 0; mi < 4; mi++)
            af[mi] = load8(&As[(wm * 64 + mi * 16 + l15) * 32 + quad * 8]);
#pragma unroll
        for (int ni = 0; ni < 4; ni++)
            bfr[ni] = load8(&Bs[(wn * 64 + ni * 16 + l15) * 32 + quad * 8]);
#pragma unroll
        for (int mi = 0; mi < 4; mi++)
#pragma unroll
            for (int ni = 0; ni < 4; ni++)
                acc[mi][ni] = __builtin_amdgcn_mfma_f32_16x16x32_bf16(af[mi], bfr[ni], acc[mi][ni], 0, 0, 0);
        __syncthreads();
    }

    if (blockIdx.z == 2) {   // V: plain row-major bf16
#pragma unroll
        for (int mi = 0; mi < 4; mi++)
#pragma unroll
            for (int ni = 0; ni < 4; ni++)
#pragma unroll
                for (int rg = 0; rg < 4; rg++) {
                    int row = tm + wm * 64 + mi * 16 + quad * 4 + rg;
                    int col = tn + wn * 64 + ni * 16 + l15;
                    Vraw[(size_t)row * N + col] = f2b(acc[mi][ni][rg]);
                }
        return;
    }

    // Q/K: rope via table + lane^1 exchange, write [b,h,s,d]
    const float qscale = (blockIdx.z == 0) ? 0.125f : 1.0f;   // fold 1/sqrt(d) into Q
    u16* dst = (blockIdx.z == 0) ? Qt : Kt;
    const int parity = l15 & 1;
#pragma unroll
    for (int mi = 0; mi < 4; mi++)
#pragma unroll
        for (int rg = 0; rg < 4; rg++) {
            const int row = tm + wm * 64 + mi * 16 + quad * 4 + rg;
            const int s  = row & (SEQQ - 1);
            const int bb = row >> 11;
#pragma unroll
            for (int ni = 0; ni < 4; ni++) {
                const int col  = tn + wn * 64 + ni * 16 + l15;
                const int dcol = col & 63;
                const int hh   = col >> 6;
                const int j    = dcol >> 1;
                const float2 cssn = tbl[s * 32 + j];
                const float mine   = acc[mi][ni][rg];
                const float theirs = __shfl_xor(mine, 1, 64);
                // even lane holds e (dcol=2j), odd holds o (dcol=2j+1)
                const float res = parity ? (theirs * cssn.y + mine * cssn.x)
                                         : (mine * cssn.x - theirs * cssn.y);
                dst[(((size_t)(bb * NHEAD + hh)) * SEQQ + s) * HDIM + dcol] = f2b(res * qscale);
            }
        }
}

// ---------------- V: [b,s,h*d] -> [b,h,d,s] transpose ----------------
__global__ __launch_bounds__(256) void vtrans(const u16* __restrict__ Vraw, u16* __restrict__ Vt)
{
    __shared__ u16 tile[64][65];
    const int s0 = blockIdx.x * 64, h = blockIdx.y, b = blockIdx.z;
    const int t = threadIdx.x;
#pragma unroll
    for (int i = 0; i < 16; i++) {
        int idx = t + i * 256;
        int sl = idx >> 6, dl = idx & 63;
        tile[sl][dl] = Vraw[((size_t)(b * SEQQ + s0 + sl)) * D_MODEL + h * HDIM + dl];
    }
    __syncthreads();
#pragma unroll
    for (int i = 0; i < 16; i++) {
        int idx = t + i * 256;
        int dl = idx >> 6, sl = idx & 63;
        Vt[(((size_t)(b * NHEAD + h)) * HDIM + dl) * SEQQ + s0 + sl] = tile[sl][dl];
    }
}

// ---------------- causal flash attention v8 (unchanged from r8: 58.8 us) ----------------
#define PSTRIDE 72
__global__ __launch_bounds__(512, 6) void attn_kernel(
    const u16* __restrict__ Qt, const u16* __restrict__ Kt, const u16* __restrict__ Vt,
    u16* __restrict__ Out)
{
    const int qblk = (gridDim.x - 1) - blockIdx.x;   // longest blocks launch first
    const int h = blockIdx.y, b = blockIdx.z;
    const int tid = threadIdx.x, w = tid >> 6, lane = tid & 63;
    const int l15 = lane & 15, quad = lane >> 4;
    const size_t bh = (size_t)(b * NHEAD + h);
    const u16* Qh = Qt + bh * SEQQ * HDIM;
    const u16* Kh = Kt + bh * SEQQ * HDIM;
    const u16* Vh = Vt + bh * HDIM * SEQQ;   // [d][s]
    const int q0w = qblk * 128 + w * 16;     // this wave's 16 q-rows
    const int tdiag = q0w >> 6;              // this wave's (single) masked tile
    const int tmax  = qblk * 2 + 1;          // last key-tile for the block

    __shared__ __attribute__((aligned(16))) u16 Ks[2][64 * 64];   // [key][dim], swizzled
    __shared__ __attribute__((aligned(16))) u16 Vs[2][64 * 64];   // [dim][key], swizzled
    __shared__ __attribute__((aligned(16))) u16 Plds[8][16 * PSTRIDE];

    short8 qf[2];
#pragma unroll
    for (int kk = 0; kk < 2; kk++)
        qf[kk] = load8(&Qh[(size_t)(q0w + l15) * HDIM + kk * 32 + quad * 8]);

    short8 ones;
#pragma unroll
    for (int i = 0; i < 8; i++) ones[i] = (short)0x3F80;  // bf16 1.0

    floatx4 O[4];
    floatx4 l_acc = {0.f, 0.f, 0.f, 0.f};
#pragma unroll
    for (int c = 0; c < 4; c++) { floatx4 z = {0.f, 0.f, 0.f, 0.f}; O[c] = z; }

    const int rr  = lane >> 3;                 // 0..7
    const int swz = ((lane & 7) ^ rr) * 8;     // swizzled col offset (u16)
    auto stage = [&](int buf, int tt) {
        const int k0s = tt * 64;
        async_cp16(Kh + (size_t)(k0s + w * 8 + rr) * HDIM + swz, &Ks[buf][w * 512]);
        async_cp16(Vh + (size_t)(w * 8 + rr) * SEQQ + k0s + swz, &Vs[buf][w * 512]);
    };

    const int sw1 = ((quad)     ^ (l15 & 7)) * 8;
    const int sw2 = ((quad + 4) ^ (l15 & 7)) * 8;

    stage(0, 0);

    for (int t = 0; t <= tmax; ++t) {
        const int cur = t & 1;
        __syncthreads();                        // staging of tile t complete
        if (t < tmax) stage(cur ^ 1, t + 1);    // async prefetch next tile

        if (t > tdiag) continue;                // wave-uniform causal skip

        const u16* KsB = &Ks[cur][0];
        const u16* VsB = &Vs[cur][0];
        const int k0 = t * 64;

        floatx4 S[4];
#pragma unroll
        for (int c = 0; c < 4; c++) {
            const int rowb = (c * 16 + l15) * 64;
            floatx4 z = {0.f, 0.f, 0.f, 0.f};
            S[c] = __builtin_amdgcn_mfma_f32_16x16x32_bf16(qf[0], load8(&KsB[rowb + sw1]), z,    0, 0, 0);
            S[c] = __builtin_amdgcn_mfma_f32_16x16x32_bf16(qf[1], load8(&KsB[rowb + sw2]), S[c], 0, 0, 0);
        }

        if (t == tdiag) {
#pragma unroll
            for (int r = 0; r < 4; r++) {
                const int q = q0w + quad * 4 + r;
#pragma unroll
                for (int c = 0; c < 4; c++)
                    if (k0 + c * 16 + l15 > q) S[c][r] = -1e30f;
            }
        }

#pragma unroll
        for (int c = 0; c < 4; c++)
#pragma unroll
            for (int r = 0; r < 4; r++)
                S[c][r] = __expf(S[c][r]);

#pragma unroll
        for (int c = 0; c < 4; c++)
#pragma unroll
            for (int r = 0; r < 4; r++)
                Plds[w][(quad * 4 + r) * PSTRIDE + c * 16 + l15] = f2b(S[c][r]);
        const short8 pf0 = load8(&Plds[w][l15 * PSTRIDE + quad * 8]);
        const short8 pf1 = load8(&Plds[w][l15 * PSTRIDE + 32 + quad * 8]);

        l_acc = __builtin_amdgcn_mfma_f32_16x16x32_bf16(pf0, ones, l_acc, 0, 0, 0);
        l_acc = __builtin_amdgcn_mfma_f32_16x16x32_bf16(pf1, ones, l_acc, 0, 0, 0);

#pragma unroll
        for (int c2 = 0; c2 < 4; c2++) {
            const int rowb = (c2 * 16 + l15) * 64;
            O[c2] = __builtin_amdgcn_mfma_f32_16x16x32_bf16(pf0, load8(&VsB[rowb + sw1]), O[c2], 0, 0, 0);
            O[c2] = __builtin_amdgcn_mfma_f32_16x16x32_bf16(pf1, load8(&VsB[rowb + sw2]), O[c2], 0, 0, 0);
        }
    }

    float inv_l[4];
#pragma unroll
    for (int r = 0; r < 4; r++) inv_l[r] = 1.0f / l_acc[r];

#pragma unroll
    for (int c2 = 0; c2 < 4; c2++)
#pragma unroll
        for (int r = 0; r < 4; r++) {
            const int q   = q0w + quad * 4 + r;
            const int col = h * HDIM + c2 * 16 + l15;
            Out[(size_t)(b * SEQQ + q) * D_MODEL + col] = f2b(O[c2][r] * inv_l[r]);
        }
}

// ---------------- o-proj GEMM: 64x128 tile (512 blocks -> 2/CU backfill) ----------------
__global__ __launch_bounds__(256) void gemm_o(
    const u16* __restrict__ A, const u16* __restrict__ Bt, float* __restrict__ C)
{
    const int K = D_MODEL, N = D_MODEL;
    __shared__ __attribute__((aligned(16))) u16 As[64 * 32];    // 4 KB
    __shared__ __attribute__((aligned(16))) u16 Bs[128 * 32];   // 8 KB

    const int tid  = threadIdx.x;
    const int w    = tid >> 6;
    const int lane = tid & 63;
    const int l15  = lane & 15;
    const int quad = lane >> 4;
    const int wm   = w >> 1, wn = w & 1;       // 2x2 waves over 64x128
    const int tm   = blockIdx.x * 64, tn = blockIdx.y * 128;

    floatx4 acc[2][4];
#pragma unroll
    for (int i = 0; i < 2; i++)
#pragma unroll
        for (int j = 0; j < 4; j++) {
            floatx4 z = {0.f, 0.f, 0.f, 0.f};
            acc[i][j] = z;
        }

    const int srow = lane >> 2;
    const int scol = (lane & 3) * 8;

    for (int k0 = 0; k0 < K; k0 += 32) {
        // 12 chunks (4 A + 8 B) over 4 waves = 3 chunks/wave
#pragma unroll
        for (int ch = w; ch < 12; ch += 4) {
            if (ch < 4) async_cp16(A  + (size_t)(tm + ch * 16 + srow) * K + k0 + scol, &As[ch * 512]);
            else        async_cp16(Bt + (size_t)(tn + (ch - 4) * 16 + srow) * K + k0 + scol, &Bs[(ch - 4) * 512]);
        }
        __syncthreads();

        short8 af[2], bfr[4];
#pragma unroll
        for (int mi = 0; mi < 2; mi++)
            af[mi] = load8(&As[(wm * 32 + mi * 16 + l15) * 32 + quad * 8]);
#pragma unroll
        for (int ni = 0; ni < 4; ni++)
            bfr[ni] = load8(&Bs[(wn * 64 + ni * 16 + l15) * 32 + quad * 8]);
#pragma unroll
        for (int mi = 0; mi < 2; mi++)
#pragma unroll
            for (int ni = 0; ni < 4; ni++)
                acc[mi][ni] = __builtin_amdgcn_mfma_f32_16x16x32_bf16(af[mi], bfr[ni], acc[mi][ni], 0, 0, 0);
        __syncthreads();
    }

#pragma unroll
    for (int mi = 0; mi < 2; mi++)
#pragma unroll
        for (int ni = 0; ni < 4; ni++)
#pragma unroll
            for (int rg = 0; rg < 4; rg++) {
                int row = tm + wm * 32 + mi * 16 + quad * 4 + rg;
                int col = tn + wn * 64 + ni * 16 + l15;
                C[(size_t)row * N + col] = acc[mi][ni][rg];
            }
}

// ---------------- launch ----------------
extern "C" void kernel_launch(void* const* d_in, const int* in_sizes, int n_in,
                              void* d_out, int out_size, void* d_ws, size_t ws_size,
                              hipStream_t stream)
{
    const float* X  = (const float*)d_in[0];
    const float* Wq = (const float*)d_in[1];
    const float* Wk = (const float*)d_in[2];
    const float* Wv = (const float*)d_in[3];
    const float* Wo = (const float*)d_in[4];
    const int* tpos = (const int*)d_in[5];
    float* out = (float*)d_out;
    char* ws = (char*)d_ws;

    const size_t MB = (size_t)1 << 20;
    u16*   Xb   = (u16*)(ws + 0);        // 8 MB; reused as Vt after gemm_qkv
    u16*   WqB  = (u16*)(ws + 8 * MB);
    u16*   WkB  = (u16*)(ws + 10 * MB);
    u16*   WvB  = (u16*)(ws + 12 * MB);
    u16*   WoB  = (u16*)(ws + 14 * MB);
    u16*   AOut = (u16*)(ws + 16 * MB);  // 8 MB (attn output)
    float2* tbl = (float2*)(ws + 24 * MB);  // 512 KB rope table
    u16*   Vraw = (u16*)(ws + 32 * MB);
    u16*   Qt   = (u16*)(ws + 40 * MB);
    u16*   Kt   = (u16*)(ws + 48 * MB);
    u16*   Vt   = Xb;

    cvt_all<<<dim3(1024, 9), 256, 0, stream>>>(X, Wq, Wk, Wv, Wo, tpos,
                                               Xb, WqB, WkB, WvB, WoB, tbl);

    gemm_qkv<<<dim3(32, 8, 3), 256, 0, stream>>>(Xb, WqB, WkB, WvB,
                                                 Qt, Kt, Vraw, tbl);
    vtrans<<<dim3(32, 16, 2), 256, 0, stream>>>(Vraw, Vt);
    attn_kernel<<<dim3(16, 16, 2), 512, 0, stream>>>(Qt, Kt, Vt, AOut);
    gemm_o<<<dim3(64, 8), 256, 0, stream>>>(AOut, WoB, out);
}

// Round 10
// 204.606 us; speedup vs baseline: 1.0408x; 1.0408x over previous
//
#include <hip/hip_runtime.h>
#include <hip/hip_bf16.h>

#define D_MODEL 1024
#define NHEAD   16
#define HDIM    64
#define SEQQ    2048
#define NBATCH  2
#define MROWS   (NBATCH * SEQQ)   // 4096

typedef unsigned short u16;
typedef __attribute__((ext_vector_type(8))) short short8;   // 8 bf16 (4 VGPRs)
typedef __attribute__((ext_vector_type(4))) float floatx4;  // 4 fp32 acc

__device__ __forceinline__ u16 f2b(float f) {
    union { __hip_bfloat16 h; u16 u; } cv;
    cv.h = __float2bfloat16(f);
    return cv.u;
}
__device__ __forceinline__ float b2f(u16 u) {
    return __uint_as_float(((unsigned int)u) << 16);
}
__device__ __forceinline__ short8 load8(const u16* p) {
    return *reinterpret_cast<const short8*>(p);
}
__device__ __forceinline__ void async_cp16(const void* g, void* l) {
    __builtin_amdgcn_global_load_lds(
        (const __attribute__((address_space(1))) void*)g,
        (__attribute__((address_space(3))) void*)l, 16, 0, 0);
}

// ---------------- fp32 -> bf16 convert: X (4 quarters) + 4 weights, one dispatch ----------------
__global__ void cvt_all(const float* __restrict__ X,
                        const float* __restrict__ w0, const float* __restrict__ w1,
                        const float* __restrict__ w2, const float* __restrict__ w3,
                        u16* __restrict__ xo,
                        u16* __restrict__ o0, u16* __restrict__ o1,
                        u16* __restrict__ o2, u16* __restrict__ o3) {
    const int z = blockIdx.y;
    const int n4 = (D_MODEL * D_MODEL) / 4;
    const float* in;
    u16* out;
    if (z < 4) { in = X + (size_t)z * n4 * 4;  out = xo + (size_t)z * n4 * 4; }
    else {
        in  = (z == 4) ? w0 : (z == 5) ? w1 : (z == 6) ? w2 : w3;
        out = (z == 4) ? o0 : (z == 5) ? o1 : (z == 6) ? o2 : o3;
    }
    const int i = blockIdx.x * 256 + threadIdx.x;
    float4 v = reinterpret_cast<const float4*>(in)[i];
    ushort4 o;
    o.x = f2b(v.x); o.y = f2b(v.y); o.z = f2b(v.z); o.w = f2b(v.w);
    reinterpret_cast<ushort4*>(out)[i] = o;
}

// ---------------- GEMM: C = A(MxK) * Bt(NxK)^T, m97-style 128x128 tile ----------------
__global__ __launch_bounds__(256) void gemm_qkv(
    const u16* __restrict__ A,
    const u16* __restrict__ B0, const u16* __restrict__ B1, const u16* __restrict__ B2,
    u16* __restrict__ C0, u16* __restrict__ C1, u16* __restrict__ C2)
{
    const int K = D_MODEL, N = D_MODEL;
    const u16* Bt = (blockIdx.z == 0) ? B0 : (blockIdx.z == 1 ? B1 : B2);
    u16*       Cp = (blockIdx.z == 0) ? C0 : (blockIdx.z == 1 ? C1 : C2);

    __shared__ __attribute__((aligned(16))) u16 As[128 * 32];
    __shared__ __attribute__((aligned(16))) u16 Bs[128 * 32];

    const int tid  = threadIdx.x;
    const int w    = tid >> 6;
    const int lane = tid & 63;
    const int l15  = lane & 15;
    const int quad = lane >> 4;
    const int wm   = w >> 1, wn = w & 1;
    const int tm   = blockIdx.x * 128, tn = blockIdx.y * 128;

    floatx4 acc[4][4];
#pragma unroll
    for (int i = 0; i < 4; i++)
#pragma unroll
        for (int j = 0; j < 4; j++) {
            floatx4 z = {0.f, 0.f, 0.f, 0.f};
            acc[i][j] = z;
        }

    const int srow = lane >> 2;
    const int scol = (lane & 3) * 8;

    for (int k0 = 0; k0 < K; k0 += 32) {
#pragma unroll
        for (int ch = w; ch < 8; ch += 4) {
            async_cp16(A  + (size_t)(tm + ch * 16 + srow) * K + k0 + scol, &As[ch * 512]);
            async_cp16(Bt + (size_t)(tn + ch * 16 + srow) * K + k0 + scol, &Bs[ch * 512]);
        }
        __syncthreads();

        short8 af[4], bfr[4];
#pragma unroll
        for (int mi = 0; mi < 4; mi++)
            af[mi] = load8(&As[(wm * 64 + mi * 16 + l15) * 32 + quad * 8]);
#pragma unroll
        for (int ni = 0; ni < 4; ni++)
            bfr[ni] = load8(&Bs[(wn * 64 + ni * 16 + l15) * 32 + quad * 8]);
#pragma unroll
        for (int mi = 0; mi < 4; mi++)
#pragma unroll
            for (int ni = 0; ni < 4; ni++)
                acc[mi][ni] = __builtin_amdgcn_mfma_f32_16x16x32_bf16(af[mi], bfr[ni], acc[mi][ni], 0, 0, 0);
        __syncthreads();
    }

#pragma unroll
    for (int mi = 0; mi < 4; mi++)
#pragma unroll
        for (int ni = 0; ni < 4; ni++)
#pragma unroll
            for (int rg = 0; rg < 4; rg++) {
                int row = tm + wm * 64 + mi * 16 + quad * 4 + rg;
                int col = tn + wn * 64 + ni * 16 + l15;
                Cp[(size_t)row * N + col] = f2b(acc[mi][ni][rg]);
            }
}

// ---------------- RoPE + [b,s,h,d] -> [b,h,s,d] transpose; Q pre-scaled by 1/sqrt(d) ----------------
__global__ void rope_qk(const u16* __restrict__ Qraw, const u16* __restrict__ Kraw,
                        const int* __restrict__ pos, u16* __restrict__ Qt, u16* __restrict__ Kt)
{
    const int gid = blockIdx.x * 256 + threadIdx.x;
    const int j = gid & 31;
    const int s = (gid >> 5) & (SEQQ - 1);
    const int h = (gid >> 16) & (NHEAD - 1);
    const int b = gid >> 20;

    const float p   = (float)pos[s];
    const float inv = expf(-(float)j * (9.210340371976184f / 32.0f));
    float sn, cs;
    sincosf(p * inv, &sn, &cs);

    const size_t ioff = ((size_t)(b * SEQQ + s)) * D_MODEL + h * HDIM + 2 * j;
    const ushort2 qp = *reinterpret_cast<const ushort2*>(&Qraw[ioff]);
    const ushort2 kp = *reinterpret_cast<const ushort2*>(&Kraw[ioff]);
    const float qe = b2f(qp.x), qo = b2f(qp.y);
    const float ke = b2f(kp.x), ko = b2f(kp.y);

    const size_t ooff = (((size_t)(b * NHEAD + h)) * SEQQ + s) * HDIM + 2 * j;
    ushort2 qr;  // fold 1/sqrt(HDIM)=0.125 into Q
    qr.x = f2b((qe * cs - qo * sn) * 0.125f);
    qr.y = f2b((qe * sn + qo * cs) * 0.125f);
    ushort2 kr;
    kr.x = f2b(ke * cs - ko * sn);
    kr.y = f2b(ke * sn + ko * cs);
    *reinterpret_cast<ushort2*>(&Qt[ooff]) = qr;
    *reinterpret_cast<ushort2*>(&Kt[ooff]) = kr;
}

// ---------------- V: [b,s,h*d] -> [b,h,d,s] transpose ----------------
__global__ __launch_bounds__(256) void vtrans(const u16* __restrict__ Vraw, u16* __restrict__ Vt)
{
    __shared__ u16 tile[64][65];
    const int s0 = blockIdx.x * 64, h = blockIdx.y, b = blockIdx.z;
    const int t = threadIdx.x;
#pragma unroll
    for (int i = 0; i < 16; i++) {
        int idx = t + i * 256;
        int sl = idx >> 6, dl = idx & 63;
        tile[sl][dl] = Vraw[((size_t)(b * SEQQ + s0 + sl)) * D_MODEL + h * HDIM + dl];
    }
    __syncthreads();
#pragma unroll
    for (int i = 0; i < 16; i++) {
        int idx = t + i * 256;
        int dl = idx >> 6, sl = idx & 63;
        Vt[(((size_t)(b * NHEAD + h)) * HDIM + dl) * SEQQ + s0 + sl] = tile[sl][dl];
    }
}

// ---------------- causal flash attention v9 ----------------
// v8 + (a) triple-buffered K/V staging (prefetch distance 2: ~1800 cyc compute
// covers DMA latency) and (b) RAW s_barrier with hand-counted s_waitcnt vmcnt:
// __syncthreads' implicit vmcnt(0) was draining the just-issued prefetch every
// tile (the r8 residual stall). Each wave has exactly 2 staging DMAs per tile,
// so barriers wait vmcnt(2) (vmcnt(0) for the last two tiles where no newer
// prefetch is in flight). P buffer un-padded (64-col rows) with the same XOR
// chunk swizzle as Ks/Vs -> LDS = 3*8K*2 + 16K = exactly 64 KB, 2 blocks/CU.
__global__ __launch_bounds__(512, 2) void attn_kernel(
    const u16* __restrict__ Qt, const u16* __restrict__ Kt, const u16* __restrict__ Vt,
    u16* __restrict__ Out)
{
    const int qblk = (gridDim.x - 1) - blockIdx.x;   // longest blocks launch first
    const int h = blockIdx.y, b = blockIdx.z;
    const int tid = threadIdx.x, w = tid >> 6, lane = tid & 63;
    const int l15 = lane & 15, quad = lane >> 4;
    const size_t bh = (size_t)(b * NHEAD + h);
    const u16* Qh = Qt + bh * SEQQ * HDIM;
    const u16* Kh = Kt + bh * SEQQ * HDIM;
    const u16* Vh = Vt + bh * HDIM * SEQQ;   // [d][s]
    const int q0w = qblk * 128 + w * 16;     // this wave's 16 q-rows
    const int tdiag = q0w >> 6;              // this wave's (single) masked tile
    const int tmax  = qblk * 2 + 1;          // last key-tile for the block

    __shared__ __attribute__((aligned(16))) u16 Ks[3][64 * 64];   // 24 KB
    __shared__ __attribute__((aligned(16))) u16 Vs[3][64 * 64];   // 24 KB
    __shared__ __attribute__((aligned(16))) u16 Plds[8][16 * 64]; // 16 KB (swizzled)

    // Q fragment loads FIRST (oldest vmcnt entries; drained by first barrier)
    short8 qf[2];
#pragma unroll
    for (int kk = 0; kk < 2; kk++)
        qf[kk] = load8(&Qh[(size_t)(q0w + l15) * HDIM + kk * 32 + quad * 8]);

    short8 ones;
#pragma unroll
    for (int i = 0; i < 8; i++) ones[i] = (short)0x3F80;  // bf16 1.0

    floatx4 O[4];
    floatx4 l_acc = {0.f, 0.f, 0.f, 0.f};
#pragma unroll
    for (int c = 0; c < 4; c++) { floatx4 z = {0.f, 0.f, 0.f, 0.f}; O[c] = z; }

    // staging: 1 K-chunk + 1 V-chunk (1 KB each) per wave per tile.
    const int rr  = lane >> 3;                 // 0..7
    const int swz = ((lane & 7) ^ rr) * 8;     // XOR-swizzled col offset (u16)
    auto stage = [&](int buf, int tt) {
        const int k0s = tt * 64;
        async_cp16(Kh + (size_t)(k0s + w * 8 + rr) * HDIM + swz, &Ks[buf][w * 512]);
        async_cp16(Vh + (size_t)(w * 8 + rr) * SEQQ + k0s + swz, &Vs[buf][w * 512]);
    };

    const int sw1 = ((quad)     ^ (l15 & 7)) * 8;
    const int sw2 = ((quad + 4) ^ (l15 & 7)) * 8;

    stage(0, 0);
    stage(1, 1);   // tmax >= 1 always

    for (int t = 0; t <= tmax; ++t) {
        const bool more = (t + 2 <= tmax);
        // barrier: stage(t) must be complete; stage(t+1) (2 DMAs) may remain in flight
        if (more) asm volatile("s_waitcnt vmcnt(2)" ::: "memory");
        else      asm volatile("s_waitcnt vmcnt(0)" ::: "memory");
        __builtin_amdgcn_s_barrier();
        if (more) stage((t + 2) % 3, t + 2);    // prefetch distance 2

        if (t > tdiag) continue;                // wave-uniform causal skip

        const u16* KsB = &Ks[t % 3][0];
        const u16* VsB = &Vs[t % 3][0];
        const int k0 = t * 64;

        floatx4 S[4];
#pragma unroll
        for (int c = 0; c < 4; c++) {
            const int rowb = (c * 16 + l15) * 64;
            floatx4 z = {0.f, 0.f, 0.f, 0.f};
            S[c] = __builtin_amdgcn_mfma_f32_16x16x32_bf16(qf[0], load8(&KsB[rowb + sw1]), z,    0, 0, 0);
            S[c] = __builtin_amdgcn_mfma_f32_16x16x32_bf16(qf[1], load8(&KsB[rowb + sw2]), S[c], 0, 0, 0);
        }

        if (t == tdiag) {
#pragma unroll
            for (int r = 0; r < 4; r++) {
                const int q = q0w + quad * 4 + r;
#pragma unroll
                for (int c = 0; c < 4; c++)
                    if (k0 + c * 16 + l15 > q) S[c][r] = -1e30f;
            }
        }

#pragma unroll
        for (int c = 0; c < 4; c++)
#pragma unroll
            for (int r = 0; r < 4; r++)
                S[c][r] = __expf(S[c][r]);

        // ---- P: C-layout -> LDS (XOR-swizzled 64-col rows) -> A-layout ----
#pragma unroll
        for (int c = 0; c < 4; c++)
#pragma unroll
            for (int r = 0; r < 4; r++) {
                const int row = quad * 4 + r;
                const int chs = ((c * 2 + (l15 >> 3)) ^ (row & 7)) * 8 + (l15 & 7);
                Plds[w][row * 64 + chs] = f2b(S[c][r]);
            }
        const short8 pf0 = load8(&Plds[w][l15 * 64 + ((quad)     ^ (l15 & 7)) * 8]);
        const short8 pf1 = load8(&Plds[w][l15 * 64 + ((quad + 4) ^ (l15 & 7)) * 8]);

        l_acc = __builtin_amdgcn_mfma_f32_16x16x32_bf16(pf0, ones, l_acc, 0, 0, 0);
        l_acc = __builtin_amdgcn_mfma_f32_16x16x32_bf16(pf1, ones, l_acc, 0, 0, 0);

#pragma unroll
        for (int c2 = 0; c2 < 4; c2++) {
            const int rowb = (c2 * 16 + l15) * 64;
            O[c2] = __builtin_amdgcn_mfma_f32_16x16x32_bf16(pf0, load8(&VsB[rowb + sw1]), O[c2], 0, 0, 0);
            O[c2] = __builtin_amdgcn_mfma_f32_16x16x32_bf16(pf1, load8(&VsB[rowb + sw2]), O[c2], 0, 0, 0);
        }
    }

    float inv_l[4];
#pragma unroll
    for (int r = 0; r < 4; r++) inv_l[r] = 1.0f / l_acc[r];

#pragma unroll
    for (int c2 = 0; c2 < 4; c2++)
#pragma unroll
        for (int r = 0; r < 4; r++) {
            const int q   = q0w + quad * 4 + r;
            const int col = h * HDIM + c2 * 16 + l15;
            Out[(size_t)(b * SEQQ + q) * D_MODEL + col] = f2b(O[c2][r] * inv_l[r]);
        }
}

// ---------------- o-proj GEMM: 64x128 tile (512 blocks -> 2/CU backfill) ----------------
__global__ __launch_bounds__(256) void gemm_o(
    const u16* __restrict__ A, const u16* __restrict__ Bt, float* __restrict__ C)
{
    const int K = D_MODEL, N = D_MODEL;
    __shared__ __attribute__((aligned(16))) u16 As[64 * 32];
    __shared__ __attribute__((aligned(16))) u16 Bs[128 * 32];

    const int tid  = threadIdx.x;
    const int w    = tid >> 6;
    const int lane = tid & 63;
    const int l15  = lane & 15;
    const int quad = lane >> 4;
    const int wm   = w >> 1, wn = w & 1;
    const int tm   = blockIdx.x * 64, tn = blockIdx.y * 128;

    floatx4 acc[2][4];
#pragma unroll
    for (int i = 0; i < 2; i++)
#pragma unroll
        for (int j = 0; j < 4; j++) {
            floatx4 z = {0.f, 0.f, 0.f, 0.f};
            acc[i][j] = z;
        }

    const int srow = lane >> 2;
    const int scol = (lane & 3) * 8;

    for (int k0 = 0; k0 < K; k0 += 32) {
#pragma unroll
        for (int ch = w; ch < 12; ch += 4) {
            if (ch < 4) async_cp16(A  + (size_t)(tm + ch * 16 + srow) * K + k0 + scol, &As[ch * 512]);
            else        async_cp16(Bt + (size_t)(tn + (ch - 4) * 16 + srow) * K + k0 + scol, &Bs[(ch - 4) * 512]);
        }
        __syncthreads();

        short8 af[2], bfr[4];
#pragma unroll
        for (int mi = 0; mi < 2; mi++)
            af[mi] = load8(&As[(wm * 32 + mi * 16 + l15) * 32 + quad * 8]);
#pragma unroll
        for (int ni = 0; ni < 4; ni++)
            bfr[ni] = load8(&Bs[(wn * 64 + ni * 16 + l15) * 32 + quad * 8]);
#pragma unroll
        for (int mi = 0; mi < 2; mi++)
#pragma unroll
            for (int ni = 0; ni < 4; ni++)
                acc[mi][ni] = __builtin_amdgcn_mfma_f32_16x16x32_bf16(af[mi], bfr[ni], acc[mi][ni], 0, 0, 0);
        __syncthreads();
    }

#pragma unroll
    for (int mi = 0; mi < 2; mi++)
#pragma unroll
        for (int ni = 0; ni < 4; ni++)
#pragma unroll
            for (int rg = 0; rg < 4; rg++) {
                int row = tm + wm * 32 + mi * 16 + quad * 4 + rg;
                int col = tn + wn * 64 + ni * 16 + l15;
                C[(size_t)row * N + col] = acc[mi][ni][rg];
            }
}

// ---------------- launch ----------------
extern "C" void kernel_launch(void* const* d_in, const int* in_sizes, int n_in,
                              void* d_out, int out_size, void* d_ws, size_t ws_size,
                              hipStream_t stream)
{
    const float* X  = (const float*)d_in[0];
    const float* Wq = (const float*)d_in[1];
    const float* Wk = (const float*)d_in[2];
    const float* Wv = (const float*)d_in[3];
    const float* Wo = (const float*)d_in[4];
    const int* tpos = (const int*)d_in[5];
    float* out = (float*)d_out;
    char* ws = (char*)d_ws;

    const size_t MB = (size_t)1 << 20;
    u16* Xb   = (u16*)(ws + 0);        // 8 MB; reused as Vt after gemm_qkv
    u16* WqB  = (u16*)(ws + 8 * MB);
    u16* WkB  = (u16*)(ws + 10 * MB);
    u16* WvB  = (u16*)(ws + 12 * MB);
    u16* WoB  = (u16*)(ws + 14 * MB);
    u16* Qraw = (u16*)(ws + 16 * MB);  // 8 MB; reused as AOut after rope
    u16* Kraw = (u16*)(ws + 24 * MB);
    u16* Vraw = (u16*)(ws + 32 * MB);
    u16* Qt   = (u16*)(ws + 40 * MB);
    u16* Kt   = (u16*)(ws + 48 * MB);
    u16* Vt   = Xb;
    u16* AOut = Qraw;

    cvt_all<<<dim3(1024, 8), 256, 0, stream>>>(X, Wq, Wk, Wv, Wo,
                                               Xb, WqB, WkB, WvB, WoB);

    gemm_qkv<<<dim3(32, 8, 3), 256, 0, stream>>>(Xb, WqB, WkB, WvB,
                                                 Qraw, Kraw, Vraw);
    rope_qk<<<8192, 256, 0, stream>>>(Qraw, Kraw, tpos, Qt, Kt);
    vtrans<<<dim3(32, 16, 2), 256, 0, stream>>>(Vraw, Vt);
    attn_kernel<<<dim3(16, 16, 2), 512, 0, stream>>>(Qt, Kt, Vt, AOut);
    gemm_o<<<dim3(64, 8), 256, 0, stream>>>(AOut, WoB, out);
}